// Round 2
// baseline (253.196 us; speedup 1.0000x reference)
//
#include <hip/hip_runtime.h>
#include <hip/hip_bf16.h>

// Problem constants (fixed by the reference setup):
//   N = 131072 rows, D = 256 cols, num_graphs = 256, n = 512 rows/graph, K = 64
#define NROWS   131072
#define D       256
#define NGRAPH  256
#define NPG     512      // rows per graph
#define KSEL    64

// ---------------------------------------------------------------------------
// Kernel 1: one wave (64 lanes) per row computes the row max.
// Lane reads float4 -> 256 floats/row, coalesced 1 KB per wave.
// ---------------------------------------------------------------------------
__global__ __launch_bounds__(256) void row_max_kernel(const float* __restrict__ feat,
                                                      float* __restrict__ scores) {
    const int gtid = blockIdx.x * blockDim.x + threadIdx.x;
    const int row  = gtid >> 6;          // wave id
    const int lane = threadIdx.x & 63;
    if (row >= NROWS) return;

    const float4 v = reinterpret_cast<const float4*>(feat + (size_t)row * D)[lane];
    float m = fmaxf(fmaxf(v.x, v.y), fmaxf(v.z, v.w));
#pragma unroll
    for (int off = 32; off > 0; off >>= 1)
        m = fmaxf(m, __shfl_xor(m, off));
    if (lane == 0) scores[row] = m;
}

// ---------------------------------------------------------------------------
// Kernel 2: one block (512 threads) per graph. Bitonic sort of the graph's
// 512 (score, local_idx) pairs, descending by score, ties -> lower index
// first (matches jax.lax.top_k). Emit global row index of the top 64.
// ---------------------------------------------------------------------------
__global__ __launch_bounds__(512) void topk_kernel(const float* __restrict__ scores,
                                                   int* __restrict__ idx_out) {
    __shared__ float s[NPG];
    __shared__ int   id[NPG];
    const int g = blockIdx.x;
    const int t = threadIdx.x;

    s[t]  = scores[g * NPG + t];
    id[t] = t;
    __syncthreads();

    // Bitonic sort under the total order: a before b  <=>
    //   (a.s > b.s) || (a.s == b.s && a.i < b.i)
    for (int k = 2; k <= NPG; k <<= 1) {
        for (int j = k >> 1; j > 0; j >>= 1) {
            const int ixj = t ^ j;
            if (ixj > t) {
                const float s1 = s[t], s2 = s[ixj];
                const int   i1 = id[t], i2 = id[ixj];
                const bool before = (s1 > s2) || (s1 == s2 && i1 < i2);
                const bool up     = ((t & k) == 0);
                if (up ? !before : before) {
                    s[t] = s2; s[ixj] = s1;
                    id[t] = i2; id[ixj] = i1;
                }
            }
            __syncthreads();
        }
    }

    if (t < KSEL) idx_out[g * KSEL + t] = g * NPG + id[t];
}

// ---------------------------------------------------------------------------
// Kernel 3: one block (256 threads) per selected row. Ascending bitonic sort
// of the 256 floats in LDS, then write to the output slot.
// Block b = g*64 + j  ->  out[g*16384 + j*256 + t] = b*256 + t (contiguous).
// ---------------------------------------------------------------------------
__global__ __launch_bounds__(256) void sort_row_kernel(const float* __restrict__ feat,
                                                       const int* __restrict__ idx,
                                                       float* __restrict__ out) {
    __shared__ float s[D];
    const int b = blockIdx.x;
    const int t = threadIdx.x;
    const int row = idx[b];

    s[t] = feat[(size_t)row * D + t];
    __syncthreads();

    for (int k = 2; k <= D; k <<= 1) {
        for (int j = k >> 1; j > 0; j >>= 1) {
            const int ixj = t ^ j;
            if (ixj > t) {
                const float a = s[t], c = s[ixj];
                const bool up = ((t & k) == 0);
                if (up ? (a > c) : (a < c)) { s[t] = c; s[ixj] = a; }
            }
            __syncthreads();
        }
    }

    out[(size_t)b * D + t] = s[t];
}

// ---------------------------------------------------------------------------
extern "C" void kernel_launch(void* const* d_in, const int* in_sizes, int n_in,
                              void* d_out, int out_size, void* d_ws, size_t ws_size,
                              hipStream_t stream) {
    const float* feat = (const float*)d_in[0];
    float* out = (float*)d_out;

    // Workspace layout: [ scores: NROWS floats | topk idx: NGRAPH*KSEL ints ]
    float* scores = (float*)d_ws;
    int*   idx    = (int*)((char*)d_ws + (size_t)NROWS * sizeof(float));

    // Stage 1: row maxes (131072 waves -> 32768 blocks of 256 threads)
    row_max_kernel<<<NROWS / 4, 256, 0, stream>>>(feat, scores);

    // Stage 2: per-graph top-64 selection (order-exact vs jax.lax.top_k)
    topk_kernel<<<NGRAPH, NPG, 0, stream>>>(scores, idx);

    // Stage 3: sort only the selected 16384 rows
    sort_row_kernel<<<NGRAPH * KSEL, D, 0, stream>>>(feat, idx, out);
}

// Round 3
// 225.302 us; speedup vs baseline: 1.1238x; 1.1238x over previous
//
#include <hip/hip_runtime.h>
#include <hip/hip_bf16.h>

// Problem constants (fixed by the reference setup):
//   N = 131072 rows, D = 256 cols, num_graphs = 256, n = 512 rows/graph, K = 64
#define NROWS   131072
#define D       256
#define NGRAPH  256
#define NPG     512      // rows per graph
#define KSEL    64

// ---------------------------------------------------------------------------
// Kernel 1: one wave computes 4 row maxes. Each lane issues 4 independent
// fully-coalesced float4 loads (4 KB in flight per wave) -> HBM-saturating.
// ---------------------------------------------------------------------------
__global__ __launch_bounds__(256) void row_max_kernel(const float* __restrict__ feat,
                                                      float* __restrict__ scores) {
    const int wave = (blockIdx.x * 256 + threadIdx.x) >> 6;   // global wave id
    const int lane = threadIdx.x & 63;
    const int row0 = wave * 4;                                 // 4 rows per wave

    const float4* p = reinterpret_cast<const float4*>(feat) + (size_t)row0 * 64 + lane;
    const float4 a = p[0], b = p[64], c = p[128], d = p[192];

    float m0 = fmaxf(fmaxf(a.x, a.y), fmaxf(a.z, a.w));
    float m1 = fmaxf(fmaxf(b.x, b.y), fmaxf(b.z, b.w));
    float m2 = fmaxf(fmaxf(c.x, c.y), fmaxf(c.z, c.w));
    float m3 = fmaxf(fmaxf(d.x, d.y), fmaxf(d.z, d.w));

#pragma unroll
    for (int off = 32; off > 0; off >>= 1) {
        m0 = fmaxf(m0, __shfl_xor(m0, off));
        m1 = fmaxf(m1, __shfl_xor(m1, off));
        m2 = fmaxf(m2, __shfl_xor(m2, off));
        m3 = fmaxf(m3, __shfl_xor(m3, off));
    }
    if (lane < 4) {
        const float m = (lane == 0) ? m0 : (lane == 1) ? m1 : (lane == 2) ? m2 : m3;
        scores[row0 + lane] = m;
    }
}

// ---------------------------------------------------------------------------
// Kernel 2: one block (512 threads) per graph. Bitonic sort of the graph's
// 512 (score, local_idx) pairs, descending by score, ties -> lower index
// first (matches jax.lax.top_k). Emit global row index of the top 64.
// (Proven absmax=0 in round 2; only ~5 us total — left unchanged.)
// ---------------------------------------------------------------------------
__global__ __launch_bounds__(512) void topk_kernel(const float* __restrict__ scores,
                                                   int* __restrict__ idx_out) {
    __shared__ float s[NPG];
    __shared__ int   id[NPG];
    const int g = blockIdx.x;
    const int t = threadIdx.x;

    s[t]  = scores[g * NPG + t];
    id[t] = t;
    __syncthreads();

    for (int k = 2; k <= NPG; k <<= 1) {
        for (int j = k >> 1; j > 0; j >>= 1) {
            const int ixj = t ^ j;
            if (ixj > t) {
                const float s1 = s[t], s2 = s[ixj];
                const int   i1 = id[t], i2 = id[ixj];
                const bool before = (s1 > s2) || (s1 == s2 && i1 < i2);
                const bool up     = ((t & k) == 0);
                if (up ? !before : before) {
                    s[t] = s2; s[ixj] = s1;
                    id[t] = i2; id[ixj] = i1;
                }
            }
            __syncthreads();
        }
    }

    if (t < KSEL) idx_out[g * KSEL + t] = g * NPG + id[t];
}

// ---------------------------------------------------------------------------
// Kernel 3: one WAVE per selected row. 256-element ascending bitonic sort
// held entirely in registers: element e = r*64 + lane, r in 0..3.
//   j < 64  -> cross-lane compare-exchange via __shfl_xor
//   j >= 64 -> pure in-lane register swap between v[r] and v[r^(j>>6)]
// Same network as the verified LDS version: for pair (e, e^j), e < e^j,
// ascending iff (e & k) == 0. Zero LDS, zero barriers.
// ---------------------------------------------------------------------------
__global__ __launch_bounds__(256) void sort_row_kernel(const float* __restrict__ feat,
                                                       const int* __restrict__ idx,
                                                       float* __restrict__ out) {
    const int wv   = threadIdx.x >> 6;
    const int lane = threadIdx.x & 63;
    const int b    = blockIdx.x * 4 + wv;        // selected-row slot, 0..16383
    const int row  = idx[b];

    const float* src = feat + (size_t)row * D;
    float v[4];
#pragma unroll
    for (int r = 0; r < 4; ++r) v[r] = src[r * 64 + lane];

#pragma unroll
    for (int k = 2; k <= 256; k <<= 1) {
#pragma unroll
        for (int j = k >> 1; j > 0; j >>= 1) {
            if (j >= 64) {
                // in-lane: partner differs in r-bit (j>>6); k is 128 or 256 here
                const int rb = j >> 6;           // 1 or 2
#pragma unroll
                for (int r = 0; r < 4; ++r) {
                    if ((r & rb) == 0) {
                        const int rp = r | rb;
                        // up = ((e_low & k) == 0); e_low = r*64+lane, k in {128,256}
                        const bool up = (k == 256) ? true : ((r & 2) == 0);
                        const float mn = fminf(v[r], v[rp]);
                        const float mx = fmaxf(v[r], v[rp]);
                        v[r]  = up ? mn : mx;
                        v[rp] = up ? mx : mn;
                    }
                }
            } else {
#pragma unroll
                for (int r = 0; r < 4; ++r) {
                    const float o = __shfl_xor(v[r], j);
                    // up = ((e & k) == 0), e = r*64 + lane
                    bool up;
                    if      (k <= 32)  up = ((lane & k) == 0);
                    else if (k == 64)  up = ((r & 1) == 0);
                    else if (k == 128) up = ((r & 2) == 0);
                    else               up = true;              // k == 256
                    const bool lower = ((lane & j) == 0);
                    const float mn = fminf(v[r], o);
                    const float mx = fmaxf(v[r], o);
                    v[r] = (up == lower) ? mn : mx;
                }
            }
        }
    }

    float* dst = out + (size_t)b * D;
#pragma unroll
    for (int r = 0; r < 4; ++r) dst[r * 64 + lane] = v[r];
}

// ---------------------------------------------------------------------------
extern "C" void kernel_launch(void* const* d_in, const int* in_sizes, int n_in,
                              void* d_out, int out_size, void* d_ws, size_t ws_size,
                              hipStream_t stream) {
    const float* feat = (const float*)d_in[0];
    float* out = (float*)d_out;

    // Workspace layout: [ scores: NROWS floats | topk idx: NGRAPH*KSEL ints ]
    float* scores = (float*)d_ws;
    int*   idx    = (int*)((char*)d_ws + (size_t)NROWS * sizeof(float));

    // Stage 1: row maxes. 4 rows/wave -> 32768 waves -> 8192 blocks of 256.
    row_max_kernel<<<NROWS / 16, 256, 0, stream>>>(feat, scores);

    // Stage 2: per-graph top-64 selection (order-exact vs jax.lax.top_k)
    topk_kernel<<<NGRAPH, NPG, 0, stream>>>(scores, idx);

    // Stage 3: register-bitonic sort of the 16384 winning rows, 1 wave/row.
    sort_row_kernel<<<NGRAPH * KSEL / 4, 256, 0, stream>>>(feat, idx, out);
}